// Round 15
// baseline (879.653 us; speedup 1.0000x reference)
//
#include <hip/hip_runtime.h>
#include <hip/hip_bf16.h>

// Problem constants
constexpr int LQ  = 1024;  // L1 == L2 == 1024
constexpr int BN  = 8;
constexpr int D1N = 512;
constexpr int D2N = 1024;
constexpr int HN  = 16;
constexpr int MN  = 1024;
constexpr int DPH = 64;

typedef __attribute__((ext_vector_type(8)))  short bf16x8;   // 8 bf16 in 4 VGPRs
typedef __attribute__((ext_vector_type(4)))  short bf16x4;   // 4 bf16 in 2 VGPRs
typedef __attribute__((ext_vector_type(2)))  float f32x2;
typedef __attribute__((ext_vector_type(4)))  float f32x4;
typedef __attribute__((ext_vector_type(16))) float f32x16;

__device__ __forceinline__ unsigned short f2bf(float f) {
  unsigned u = __float_as_uint(f);
  u += 0x7FFFu + ((u >> 16) & 1u);   // RNE
  return (unsigned short)(u >> 16);
}
__device__ __forceinline__ float bf2f(unsigned short u) {
  return __uint_as_float(((unsigned)u) << 16);
}
__device__ __forceinline__ float rcpf(float x) {
  float r;
  asm("v_rcp_f32 %0, %1" : "=v"(r) : "v"(x));
  return r;
}

__device__ __forceinline__ f32x4 mfma16(bf16x8 a, bf16x8 b, f32x4 c) {
  return __builtin_amdgcn_mfma_f32_16x16x32_bf16(a, b, c, 0, 0, 0);
}
__device__ __forceinline__ f32x16 mfma32(bf16x8 a, bf16x8 b, f32x16 c) {
  return __builtin_amdgcn_mfma_f32_32x32x16_bf16(a, b, c, 0, 0, 0);
}
__device__ __forceinline__ f32x16 zero16() {
  f32x16 z;
#pragma unroll
  for (int i = 0; i < 16; ++i) z[i] = 0.f;
  return z;
}

__device__ __forceinline__ unsigned cvtpk(float lo, float hi) {
  unsigned r;
  asm("v_cvt_pk_bf16_f32 %0, %1, %2" : "=v"(r) : "v"(lo), "v"(hi));
  return r;
}

// LDS-visibility barrier WITHOUT the vmcnt(0) drain __syncthreads() emits.
// (Correctness-proven R7-R14.)
__device__ __forceinline__ void lds_barrier() {
  asm volatile("s_waitcnt lgkmcnt(0)" ::: "memory");
  __builtin_amdgcn_s_barrier();
}

// Build PV A-fragment from 8 P values (C-layout row=(reg&3)+8*(reg>>2)+4*(lane>>5)).
__device__ __forceinline__ bf16x8 pfrag(const float* p) {
  unsigned x0 = cvtpk(p[0], p[1]), y0 = cvtpk(p[4], p[5]);
  unsigned x1 = cvtpk(p[2], p[3]), y1 = cvtpk(p[6], p[7]);
  asm volatile("v_permlane32_swap_b32 %0, %1" : "+v"(x0), "+v"(y0));
  asm volatile("v_permlane32_swap_b32 %0, %1" : "+v"(x1), "+v"(y1));
  union { unsigned u[4]; bf16x8 v; } r;
  r.u[0] = x0; r.u[1] = x1; r.u[2] = y0; r.u[3] = y1;
  return r.v;
}

__device__ __forceinline__ bf16x8 pack8(f32x4 p0, f32x4 p1) {
  bf16x8 o;
  o[0] = (short)f2bf(p0[0]); o[1] = (short)f2bf(p0[1]);
  o[2] = (short)f2bf(p0[2]); o[3] = (short)f2bf(p0[3]);
  o[4] = (short)f2bf(p1[0]); o[5] = (short)f2bf(p1[1]);
  o[6] = (short)f2bf(p1[2]); o[7] = (short)f2bf(p1[3]);
  return o;
}
// Fast frag-convert via v_cvt_pk_bf16_f32 (RNE)
__device__ __forceinline__ bf16x8 pack8q(f32x4 lo, f32x4 hi) {
  union { unsigned u[4]; bf16x8 v; } r;
  r.u[0] = cvtpk(lo[0], lo[1]); r.u[1] = cvtpk(lo[2], lo[3]);
  r.u[2] = cvtpk(hi[0], hi[1]); r.u[3] = cvtpk(hi[2], hi[3]);
  return r.v;
}

// ---------------------------------------------------------------- cvt f32->bf16
__global__ __launch_bounds__(256) void cvt_kernel(const float* __restrict__ src,
                                                  unsigned short* __restrict__ dst,
                                                  int n8) {
  int i = blockIdx.x * blockDim.x + threadIdx.x;
  if (i >= n8) return;
  const f32x4* s = (const f32x4*)src;
  f32x4 x = s[2 * i], y = s[2 * i + 1];
  ((bf16x8*)dst)[i] = pack8(x, y);
}

// ---------------------------------------------------------------- add partials
// c21(bf16) = bf16( f32(p0) + f32(p1) )   (bf16 q-half partials)
__global__ __launch_bounds__(256) void addcvt_kernel(const unsigned short* __restrict__ p0,
                                                     const unsigned short* __restrict__ p1,
                                                     unsigned short* __restrict__ dst,
                                                     int n8) {
  int i = blockIdx.x * blockDim.x + threadIdx.x;
  if (i >= n8) return;
  bf16x8 a = ((const bf16x8*)p0)[i];
  bf16x8 b = ((const bf16x8*)p1)[i];
  bf16x8 o;
#pragma unroll
  for (int j = 0; j < 8; ++j)
    o[j] = (short)f2bf(bf2f((unsigned short)a[j]) + bf2f((unsigned short)b[j]));
  ((bf16x8*)dst)[i] = o;
}

// ---------------------------------------------------------------- staged GEMM
// A [rows,K] row-major (f32 if AF32, else bf16); W [1024,K] bf16 row-major.
// C = A @ W^T + bias. 128x128 tile, BK=32, reg-staged LDS, 2-phase with
// lgkmcnt-only barriers (R8-validated). AF32: cvt folded into LDS write.
// MODE 0: bf16 to [B,H,L,64]; MODE 2: f32 row-major [rows,1024]
template <int K, int MODE, bool AF32>
__device__ __forceinline__ void gemm_body(const void* __restrict__ Ap,
                                          const unsigned short* __restrict__ W,
                                          const float* __restrict__ bias,
                                          void* __restrict__ outp,
                                          int rowb, int colb) {
  __shared__ unsigned short As[128 * 40], Bs[128 * 40];
  const int tid = threadIdx.x, wave = tid >> 6, lane = tid & 63;
  const int lg = lane >> 4, lm = lane & 15;
  const int wrow = (wave >> 1) * 64, wcol = (wave & 1) * 64;
  const int sr = tid >> 1, sh = (tid & 1) * 16;
  const unsigned short* Arow = AF32 ? nullptr
      : (const unsigned short*)Ap + (size_t)(rowb + sr) * K + sh;
  const float* ArowF = AF32 ? (const float*)Ap + (size_t)(rowb + sr) * K + sh
                            : nullptr;
  const unsigned short* Wrow = W + (size_t)(colb + sr) * K + sh;

  f32x4 acc[4][4];
#pragma unroll
  for (int i = 0; i < 4; ++i)
#pragma unroll
    for (int j = 0; j < 4; ++j) acc[i][j] = (f32x4){0.f, 0.f, 0.f, 0.f};

  f32x4 fa0, fa1, fa2, fa3;
  bf16x8 a0, a1, b0, b1;
  if (AF32) {
    fa0 = *(const f32x4*)(ArowF);     fa1 = *(const f32x4*)(ArowF + 4);
    fa2 = *(const f32x4*)(ArowF + 8); fa3 = *(const f32x4*)(ArowF + 12);
  } else {
    a0 = *(const bf16x8*)(Arow);
    a1 = *(const bf16x8*)(Arow + 8);
  }
  b0 = *(const bf16x8*)(Wrow);
  b1 = *(const bf16x8*)(Wrow + 8);

  for (int kk = 0; kk < K; kk += 32) {
    lds_barrier();   // previous iteration's LDS frag reads complete
    if (AF32) {
      *(bf16x8*)&As[sr * 40 + sh]     = pack8q(fa0, fa1);
      *(bf16x8*)&As[sr * 40 + sh + 8] = pack8q(fa2, fa3);
    } else {
      *(bf16x8*)&As[sr * 40 + sh] = a0;
      *(bf16x8*)&As[sr * 40 + sh + 8] = a1;
    }
    *(bf16x8*)&Bs[sr * 40 + sh] = b0;
    *(bf16x8*)&Bs[sr * 40 + sh + 8] = b1;
    const int kn = (kk + 32 < K) ? kk + 32 : 0;   // clamped harmless reload
    if (AF32) {
      fa0 = *(const f32x4*)(ArowF + kn);     fa1 = *(const f32x4*)(ArowF + kn + 4);
      fa2 = *(const f32x4*)(ArowF + kn + 8); fa3 = *(const f32x4*)(ArowF + kn + 12);
    } else {
      a0 = *(const bf16x8*)(Arow + kn);
      a1 = *(const bf16x8*)(Arow + kn + 8);
    }
    b0 = *(const bf16x8*)(Wrow + kn);
    b1 = *(const bf16x8*)(Wrow + kn + 8);
    lds_barrier();   // staged writes visible
    bf16x8 af[4], wf[4];
#pragma unroll
    for (int i = 0; i < 4; ++i) af[i] = *(const bf16x8*)&As[(wrow + i * 16 + lm) * 40 + lg * 8];
#pragma unroll
    for (int j = 0; j < 4; ++j) wf[j] = *(const bf16x8*)&Bs[(wcol + j * 16 + lm) * 40 + lg * 8];
#pragma unroll
    for (int i = 0; i < 4; ++i)
#pragma unroll
      for (int j = 0; j < 4; ++j) acc[i][j] = mfma16(af[i], wf[j], acc[i][j]);
  }

#pragma unroll
  for (int j = 0; j < 4; ++j) {
    int col = colb + wcol + j * 16 + lm;
    float bs = bias[col];
#pragma unroll
    for (int i = 0; i < 4; ++i) {
#pragma unroll
      for (int r = 0; r < 4; ++r) {
        int row = rowb + wrow + i * 16 + lg * 4 + r;
        float v = acc[i][j][r] + bs;
        if (MODE == 0) {
          int l = row >> 3, bb = row & 7, h = col >> 6, d = col & 63;
          ((unsigned short*)outp)[(((size_t)(bb * HN + h)) * LQ + l) * DPH + d] = f2bf(v);
        } else {
          ((float*)outp)[(size_t)row * MN + col] = v;
        }
      }
    }
  }
}

// Paired projections (f32 A, cvt folded). sel in blockIdx.y-MSB so the K/V
// pair sharing an A-panel has the SAME blockIdx.x -> same XCD (R14).
template <int K>
__global__ __launch_bounds__(256) void gemm_pair_f32_kernel(
    const float* __restrict__ A,
    const unsigned short* __restrict__ W0, const unsigned short* __restrict__ W1,
    const float* __restrict__ b0, const float* __restrict__ b1,
    void* __restrict__ o0, void* __restrict__ o1) {
  const int sel = blockIdx.y >> 3;
  gemm_body<K, 0, true>(A, sel ? W1 : W0, sel ? b1 : b0, sel ? o1 : o0,
                        blockIdx.x * 128, (blockIdx.y & 7) * 128);
}

// Dual final projections in one dispatch: blockIdx.y>=8 -> second problem.
template <int K>
__global__ __launch_bounds__(256) void gemm_dual_kernel(
    const unsigned short* __restrict__ A0, const unsigned short* __restrict__ A1,
    const unsigned short* __restrict__ W0, const unsigned short* __restrict__ W1,
    const float* __restrict__ b0, const float* __restrict__ b1,
    void* __restrict__ o0, void* __restrict__ o1) {
  const int sel = blockIdx.y >> 3;
  gemm_body<K, 2, false>(sel ? A1 : A0, sel ? W1 : W0, sel ? b1 : b0,
                         sel ? o1 : o0, blockIdx.x * 128, (blockIdx.y & 7) * 128);
}

// ---------------------------------------------------------------- V transpose
// V [BH, L, 64] bf16 -> VT [BH, 64, L]; optional per-source-row scale (1/colsum)
__global__ __launch_bounds__(256) void transpose_kernel(const unsigned short* __restrict__ V,
                                                        unsigned short* __restrict__ VT,
                                                        const float* __restrict__ scale) {
  __shared__ unsigned short t[64][72];
  int bh = blockIdx.y, l0 = blockIdx.x * 64;
  int tid = threadIdx.x;
  int r = tid >> 2, c0 = (tid & 3) * 16;
  const unsigned short* src = V + ((size_t)bh * LQ + l0 + r) * DPH + c0;
  bf16x8 v0 = *(const bf16x8*)(src);
  bf16x8 v1 = *(const bf16x8*)(src + 8);
  if (scale) {
    float sc = scale[(size_t)bh * LQ + l0 + r];
#pragma unroll
    for (int j = 0; j < 8; ++j) {
      v0[j] = (short)f2bf(bf2f((unsigned short)v0[j]) * sc);
      v1[j] = (short)f2bf(bf2f((unsigned short)v1[j]) * sc);
    }
  }
  *(bf16x8*)&t[r][c0] = v0;
  *(bf16x8*)&t[r][c0 + 8] = v1;
  __syncthreads();
  int d = tid >> 2, lc = (tid & 3) * 16;
  bf16x8 o0, o1;
#pragma unroll
  for (int j = 0; j < 8; ++j) {
    o0[j] = (short)t[lc + j][d];
    o1[j] = (short)t[lc + 8 + j][d];
  }
  unsigned short* dst = VT + ((size_t)bh * DPH + d) * LQ + l0 + lc;
  *(bf16x8*)dst = o0;
  *(bf16x8*)(dst + 8) = o1;
}

// ---------------------------------------------------------------- col reduce
// inv_colsum[bh,k] = 1/sum_q exp(s[q,k]).  bh-major grid (R14, XCD-local).
__global__ __launch_bounds__(256) void col_reduce_kernel(const unsigned short* __restrict__ K1p,
                                                         const unsigned short* __restrict__ K2p,
                                                         float* __restrict__ inv_colsum) {
  int bh = blockIdx.x, kb = blockIdx.y * 128;
  int wave = threadIdx.x >> 6, lane = threadIdx.x & 63, l31 = lane & 31, sg = lane >> 5;
  int k0w = kb + wave * 32;
  const unsigned short* k1 = K1p + (size_t)bh * LQ * DPH;
  const unsigned short* k2 = K2p + (size_t)bh * LQ * DPH;
  bf16x8 bk[4];
#pragma unroll
  for (int i = 0; i < 4; ++i)
    bk[i] = *(const bf16x8*)(k1 + (size_t)(k0w + l31) * DPH + i * 16 + sg * 8);
  float tot = 0.f;
  for (int q0 = 0; q0 < LQ; q0 += 32) {
    bf16x8 aq[4];
#pragma unroll
    for (int i = 0; i < 4; ++i)
      aq[i] = *(const bf16x8*)(k2 + (size_t)(q0 + l31) * DPH + i * 16 + sg * 8);
    f32x16 cs = zero16();
#pragma unroll
    for (int i = 0; i < 4; ++i) cs = mfma32(aq[i], bk[i], cs);
#pragma unroll
    for (int r = 0; r < 16; ++r) tot += __expf(cs[r]);
  }
  tot += __shfl_xor(tot, 32);
  if (lane < 32) inv_colsum[(size_t)bh * LQ + k0w + lane] = 1.0f / tot;
}

// ---------------------------------------------------------------- ctx 1->2
// out[q][d] = sum_k exp(s[q,k]) * V1s[k][d]   (V1s pre-scaled by 1/colsum)
// bh-major grid (R14, XCD-local).
__global__ __launch_bounds__(256) void ctx12_kernel(const unsigned short* __restrict__ K1p,
                                                    const unsigned short* __restrict__ K2p,
                                                    const unsigned short* __restrict__ V1Ts,
                                                    unsigned short* __restrict__ c12) {
  int bh = blockIdx.x, b = bh >> 4, h = bh & 15;
  int wave = threadIdx.x >> 6, lane = threadIdx.x & 63, l31 = lane & 31, sg = lane >> 5;
  int q0 = blockIdx.y * 128 + wave * 32;
  const unsigned short* k1 = K1p + (size_t)bh * LQ * DPH;
  const unsigned short* k2 = K2p + (size_t)bh * LQ * DPH;
  const unsigned short* vt = V1Ts + (size_t)bh * DPH * LQ;

  bf16x8 bq[4];  // K2 rows q (B operand of score), hoisted
#pragma unroll
  for (int i = 0; i < 4; ++i)
    bq[i] = *(const bf16x8*)(k2 + (size_t)(q0 + l31) * DPH + i * 16 + sg * 8);

  f32x16 acc0 = zero16(), acc1 = zero16();
  for (int k0 = 0; k0 < LQ; k0 += 32) {
    bf16x8 ak[4];
#pragma unroll
    for (int i = 0; i < 4; ++i)
      ak[i] = *(const bf16x8*)(k1 + (size_t)(k0 + l31) * DPH + i * 16 + sg * 8);
    f32x16 cs = zero16();
#pragma unroll
    for (int i = 0; i < 4; ++i) cs = mfma32(ak[i], bq[i], cs);  // C[k][q]
    float p[16];
#pragma unroll
    for (int r = 0; r < 16; ++r) p[r] = __expf(cs[r]);
    bf16x8 pa0 = pfrag(p), pa1 = pfrag(p + 8);
    bf16x8 v00 = *(const bf16x8*)(vt + (size_t)l31 * LQ + k0 + sg * 8);
    bf16x8 v01 = *(const bf16x8*)(vt + (size_t)l31 * LQ + k0 + 16 + sg * 8);
    bf16x8 v10 = *(const bf16x8*)(vt + (size_t)(32 + l31) * LQ + k0 + sg * 8);
    bf16x8 v11 = *(const bf16x8*)(vt + (size_t)(32 + l31) * LQ + k0 + 16 + sg * 8);
    acc0 = mfma32(pa0, v00, acc0);
    acc0 = mfma32(pa1, v01, acc0);
    acc1 = mfma32(pa0, v10, acc1);
    acc1 = mfma32(pa1, v11, acc1);
  }
#pragma unroll
  for (int r = 0; r < 16; ++r) {
    int q = q0 + (r & 3) + 8 * (r >> 2) + 4 * sg;
    size_t base = ((size_t)q * BN + b) * MN + h * 64;
    c12[base + l31] = f2bf(acc0[r]);
    c12[base + 32 + l31] = f2bf(acc1[r]);
  }
}

// ---------------------------------------------------------------- ctx 2->1
// v8 = R8's v4 step structure + CO-RESIDENCY exact-fit (R14 lesson: 1 blk/CU
// left ~75% idle; R11's split failed because 74KB/64VGPR blocks can't pair):
//   * strip stored as BF16 (SPB=36 pad): LDS 36.9KB + f32 tot 4.6KB = 41.5KB
//     -> two 1024-thread blocks/CU (83KB < 160KB).
//   * __launch_bounds__(1024, 8): forces VGPR<=64 -> 32 waves/CU exact fit.
//   * q-split blockIdx.z in {0,1} (R11-verified independent halves) -> grid
//     512 = 2 blocks/CU; bf16 partials merged by addcvt (+~8us).
// Precision: bf16 strip only affects the h-sum terms (~0.4%); output margin
// is 2.7x. pex stays f32 in regs.
__global__ __launch_bounds__(1024, 8) void ctx21_part_kernel(const unsigned short* __restrict__ K1p,
                                                             const unsigned short* __restrict__ K2p,
                                                             const unsigned short* __restrict__ V2T,
                                                             unsigned short* __restrict__ part) {
  constexpr int SPB = 36;               // bf16 per k-row (32 q + 4 pad; 72B, 8B-aligned rows)
  constexpr int WSB = 32 * SPB;         // bf16 per wave strip
  constexpr int SPT = 36;               // f32 per k-row of tot (144B rows, 16B-aligned)
  __shared__ unsigned short stripb[16 * WSB];  // 36864 B
  __shared__ float tot[32 * SPT];              // 4608 B  (total 41472 B)
  const int b = blockIdx.x, kb = blockIdx.y, qh = blockIdx.z;   // grid (8,32,2)
  const int tid = threadIdx.x, wave = tid >> 6, lane = tid & 63;
  const int l31 = lane & 31, sg = lane >> 5;
  const int h = wave, bh = b * HN + h;
  const int k0 = kb * 32;
  const unsigned short* k1 = K1p + (size_t)bh * LQ * DPH;
  const unsigned short* k2 = K2p + (size_t)bh * LQ * DPH;
  const unsigned short* vt = V2T + (size_t)bh * DPH * LQ;
  unsigned short* mystrip = &stripb[wave * WSB];

  const int tbeg = qh * 16, tend = tbeg + 16;   // q in [qh*512, qh*512+512)
  // stage-B map: 256 threads, each (k, q-quad): 16 bf16x4 reads
  const int bk_ = tid & 31, bq4 = (tid >> 5) * 4;

  bf16x8 bk[4];  // K1 rows k (score B operand), fixed for whole kernel
#pragma unroll
  for (int i = 0; i < 4; ++i)
    bk[i] = *(const bf16x8*)(k1 + (size_t)(k0 + l31) * DPH + i * 16 + sg * 8);

  // prologue: K2 fragments for first q-step of this half
  bf16x8 aq[4];
#pragma unroll
  for (int i = 0; i < 4; ++i)
    aq[i] = *(const bf16x8*)(k2 + (size_t)(tbeg * 32 + l31) * DPH + i * 16 + sg * 8);

  f32x16 acc0 = zero16(), acc1 = zero16();

  for (int t = tbeg; t < tend; ++t) {
    const int q0 = t * 32;
    // ---- stage A: scores (prefetched frags), exp, bf16 strip write
    f32x16 cs = zero16();
#pragma unroll
    for (int i = 0; i < 4; ++i) cs = mfma32(aq[i], bk[i], cs);  // C[row=q][col=k]
    const int qn = ((t + 1) & 31) * 32;   // harmless garbage prefetch on last
#pragma unroll
    for (int i = 0; i < 4; ++i)
      aq[i] = *(const bf16x8*)(k2 + (size_t)(qn + l31) * DPH + i * 16 + sg * 8);
    float pex[16];
#pragma unroll
    for (int r = 0; r < 16; ++r) pex[r] = __expf(cs[r]);
#pragma unroll
    for (int g = 0; g < 4; ++g) {         // q-group g covers q = g*8+4sg ..+3
      int qb = g * 8 + 4 * sg;
      *(unsigned*)&mystrip[l31 * SPB + qb]     = cvtpk(pex[4 * g],     pex[4 * g + 1]);
      *(unsigned*)&mystrip[l31 * SPB + qb + 2] = cvtpk(pex[4 * g + 2], pex[4 * g + 3]);
    }
    // V loads issued here; consumed after barrier B (vmcnt NOT drained at bar)
    bf16x8 v00 = *(const bf16x8*)(vt + (size_t)l31 * LQ + q0 + sg * 8);
    bf16x8 v01 = *(const bf16x8*)(vt + (size_t)l31 * LQ + q0 + 16 + sg * 8);
    bf16x8 v10 = *(const bf16x8*)(vt + (size_t)(32 + l31) * LQ + q0 + sg * 8);
    bf16x8 v11 = *(const bf16x8*)(vt + (size_t)(32 + l31) * LQ + q0 + 16 + sg * 8);
    lds_barrier();  // A: strips visible
    // ---- stage B: 256 threads, each sums one (k, q-quad) over 16 strips
    if (tid < 256) {
      int off = bk_ * SPB + bq4;
      f32x4 s = (f32x4){0.f, 0.f, 0.f, 0.f};
#pragma unroll
      for (int w = 0; w < 16; ++w) {
        bf16x4 v = *(const bf16x4*)&stripb[w * WSB + off];
        s[0] += bf2f((unsigned short)v[0]);
        s[1] += bf2f((unsigned short)v[1]);
        s[2] += bf2f((unsigned short)v[2]);
        s[3] += bf2f((unsigned short)v[3]);
      }
      f32x4 rc;
#pragma unroll
      for (int j = 0; j < 4; ++j) rc[j] = rcpf(s[j]);
      *(f32x4*)&tot[bk_ * SPT + bq4] = rc;
    }
    lds_barrier();  // B: tot visible
    // ---- stage C: tot reads, normalize in-reg (f32 pex), pfrag, PV MFMA
    float p8a[8], p8b[8];
#pragma unroll
    for (int g = 0; g < 4; ++g) {
      int qb = g * 8 + 4 * sg;
      f32x2 t0 = *(const f32x2*)&tot[l31 * SPT + qb];
      f32x2 t1 = *(const f32x2*)&tot[l31 * SPT + qb + 2];
      float* dstp = (g < 2) ? &p8a[(g & 1) * 4] : &p8b[(g & 1) * 4];
      dstp[0] = pex[4 * g]     * t0.x;
      dstp[1] = pex[4 * g + 1] * t0.y;
      dstp[2] = pex[4 * g + 2] * t1.x;
      dstp[3] = pex[4 * g + 3] * t1.y;
    }
    bf16x8 pa0 = pfrag(p8a), pa1 = pfrag(p8b);
    acc0 = mfma32(pa0, v00, acc0);
    acc0 = mfma32(pa1, v01, acc0);
    acc1 = mfma32(pa0, v10, acc1);
    acc1 = mfma32(pa1, v11, acc1);
  }
  // bf16 partial write for this q-half
  unsigned short* dst = part + (size_t)qh * (8192 * (size_t)MN);
#pragma unroll
  for (int r = 0; r < 16; ++r) {
    int k = k0 + (r & 3) + 8 * (r >> 2) + 4 * sg;
    size_t base = ((size_t)k * BN + b) * MN + h * 64;
    dst[base + l31] = f2bf(acc0[r]);
    dst[base + 32 + l31] = f2bf(acc1[r]);
  }
}

// ================================================================ host
extern "C" void kernel_launch(void* const* d_in, const int* in_sizes, int n_in,
                              void* d_out, int out_size, void* d_ws, size_t ws_size,
                              hipStream_t stream) {
  const float* ctx1 = (const float*)d_in[0];
  const float* ctx2 = (const float*)d_in[1];
  const float* Wk1 = (const float*)d_in[2];  const float* bk1 = (const float*)d_in[3];
  const float* Wv1 = (const float*)d_in[4];  const float* bv1 = (const float*)d_in[5];
  const float* Wk2 = (const float*)d_in[6];  const float* bk2 = (const float*)d_in[7];
  const float* Wv2 = (const float*)d_in[8];  const float* bv2 = (const float*)d_in[9];
  const float* Wf12 = (const float*)d_in[10]; const float* bf12 = (const float*)d_in[11];
  const float* Wf21 = (const float*)d_in[12]; const float* bf21 = (const float*)d_in[13];

  char* ws = (char*)d_ws;
  size_t off = 0;
  auto alloc = [&](size_t bytes) {
    void* p = ws + off;
    off += (bytes + 255) & ~(size_t)255;
    return p;
  };
  const size_t KV_BYTES = (size_t)BN * HN * LQ * DPH * 2;  // 16.78 MB

  unsigned short* wk1b = (unsigned short*)alloc((size_t)MN * D1N * 2);
  unsigned short* wv1b = (unsigned short*)alloc((size_t)MN * D1N * 2);
  unsigned short* wk2b = (unsigned short*)alloc((size_t)MN * D2N * 2);
  unsigned short* wv2b = (unsigned short*)alloc((size_t)MN * D2N * 2);
  unsigned short* wf12b = (unsigned short*)alloc((size_t)MN * MN * 2);
  unsigned short* wf21b = (unsigned short*)alloc((size_t)MN * MN * 2);
  unsigned short* K1buf = (unsigned short*)alloc(KV_BYTES);
  unsigned short* K2buf = (unsigned short*)alloc(KV_BYTES);
  unsigned short* V1T = (unsigned short*)alloc(KV_BYTES);   // scaled by 1/colsum
  unsigned short* V2T = (unsigned short*)alloc(KV_BYTES);
  float* invcs = (float*)alloc((size_t)BN * HN * LQ * 4);
  unsigned short* c12 = (unsigned short*)alloc(KV_BYTES);
  unsigned short* c21 = (unsigned short*)alloc(KV_BYTES);
  unsigned short* c21p = (unsigned short*)alloc((size_t)2 * 8192 * MN * 2);  // bf16 partials
  unsigned short* V1tmp = c12;  // alias: dead before c12 written
  unsigned short* V2tmp = c21;

  // ---- phase 1: weight f32 -> bf16 conversions (ctx cvt folded into GEMM)
  auto cvt = [&](const float* s, unsigned short* d, int n) {
    int n8 = n / 8;
    cvt_kernel<<<(n8 + 255) / 256, 256, 0, stream>>>(s, d, n8);
  };
  cvt(Wk1, wk1b, MN * D1N);
  cvt(Wv1, wv1b, MN * D1N);
  cvt(Wk2, wk2b, MN * D2N);
  cvt(Wv2, wv2b, MN * D2N);
  cvt(Wf12, wf12b, MN * MN);
  cvt(Wf21, wf21b, MN * MN);

  // ---- phase 2: projections, K/V paired per context (sel in y-MSB), f32 A
  gemm_pair_f32_kernel<D1N><<<dim3(64, 16), 256, 0, stream>>>(
      ctx1, wk1b, wv1b, bk1, bv1, K1buf, V1tmp);
  gemm_pair_f32_kernel<D2N><<<dim3(64, 16), 256, 0, stream>>>(
      ctx2, wk2b, wv2b, bk2, bv2, K2buf, V2tmp);

  // ---- phase 3: colsum reduction (bh-major grid), then V transposes
  col_reduce_kernel<<<dim3(BN * HN, LQ / 128), 256, 0, stream>>>(K1buf, K2buf, invcs);
  dim3 gt(LQ / 64, BN * HN);
  transpose_kernel<<<gt, 256, 0, stream>>>(V1tmp, V1T, invcs);
  transpose_kernel<<<gt, 256, 0, stream>>>(V2tmp, V2T, nullptr);

  // ---- phase 4: context passes (ctx21: q-split, 2 blocks/CU exact fit)
  ctx12_kernel<<<dim3(BN * HN, LQ / 128), 256, 0, stream>>>(K1buf, K2buf, V1T, c12);
  ctx21_part_kernel<<<dim3(BN, LQ / 32, 2), 1024, 0, stream>>>(K1buf, K2buf, V2T, c21p);
  addcvt_kernel<<<(8192 * MN / 8 + 255) / 256, 256, 0, stream>>>(
      c21p, c21p + (size_t)8192 * MN, c21, 8192 * MN / 8);

  // ---- phase 5: both final projections in ONE dispatch -> f32 d_out
  float* out0 = (float*)d_out;                 // [L1, B, M] (context_2_to_1)
  float* out1 = out0 + (size_t)LQ * BN * MN;   // [L2, B, M] (context_1_to_2)
  gemm_dual_kernel<MN><<<dim3(64, 16), 256, 0, stream>>>(
      c21, c12, wf21b, wf12b, bf21, bf12, out0, out1);
}

// Round 17
// 505.663 us; speedup vs baseline: 1.7396x; 1.7396x over previous
//
#include <hip/hip_runtime.h>
#include <hip/hip_bf16.h>

// Problem constants
constexpr int LQ  = 1024;  // L1 == L2 == 1024
constexpr int BN  = 8;
constexpr int D1N = 512;
constexpr int D2N = 1024;
constexpr int HN  = 16;
constexpr int MN  = 1024;
constexpr int DPH = 64;

typedef __attribute__((ext_vector_type(8)))  short bf16x8;   // 8 bf16 in 4 VGPRs
typedef __attribute__((ext_vector_type(4)))  short bf16x4;   // 4 bf16 in 2 VGPRs
typedef __attribute__((ext_vector_type(2)))  float f32x2;
typedef __attribute__((ext_vector_type(4)))  float f32x4;
typedef __attribute__((ext_vector_type(16))) float f32x16;

__device__ __forceinline__ unsigned short f2bf(float f) {
  unsigned u = __float_as_uint(f);
  u += 0x7FFFu + ((u >> 16) & 1u);   // RNE
  return (unsigned short)(u >> 16);
}
__device__ __forceinline__ float bf2f(unsigned short u) {
  return __uint_as_float(((unsigned)u) << 16);
}
__device__ __forceinline__ float rcpf(float x) {
  float r;
  asm("v_rcp_f32 %0, %1" : "=v"(r) : "v"(x));
  return r;
}

__device__ __forceinline__ f32x4 mfma16(bf16x8 a, bf16x8 b, f32x4 c) {
  return __builtin_amdgcn_mfma_f32_16x16x32_bf16(a, b, c, 0, 0, 0);
}
__device__ __forceinline__ f32x16 mfma32(bf16x8 a, bf16x8 b, f32x16 c) {
  return __builtin_amdgcn_mfma_f32_32x32x16_bf16(a, b, c, 0, 0, 0);
}
__device__ __forceinline__ f32x16 zero16() {
  f32x16 z;
#pragma unroll
  for (int i = 0; i < 16; ++i) z[i] = 0.f;
  return z;
}

__device__ __forceinline__ unsigned cvtpk(float lo, float hi) {
  unsigned r;
  asm("v_cvt_pk_bf16_f32 %0, %1, %2" : "=v"(r) : "v"(lo), "v"(hi));
  return r;
}

// LDS-visibility barrier WITHOUT the vmcnt(0) drain __syncthreads() emits.
// (Correctness-proven R7-R15.)
__device__ __forceinline__ void lds_barrier() {
  asm volatile("s_waitcnt lgkmcnt(0)" ::: "memory");
  __builtin_amdgcn_s_barrier();
}

// Build PV A-fragment from 8 P values (C-layout row=(reg&3)+8*(reg>>2)+4*(lane>>5)).
__device__ __forceinline__ bf16x8 pfrag(const float* p) {
  unsigned x0 = cvtpk(p[0], p[1]), y0 = cvtpk(p[4], p[5]);
  unsigned x1 = cvtpk(p[2], p[3]), y1 = cvtpk(p[6], p[7]);
  asm volatile("v_permlane32_swap_b32 %0, %1" : "+v"(x0), "+v"(y0));
  asm volatile("v_permlane32_swap_b32 %0, %1" : "+v"(x1), "+v"(y1));
  union { unsigned u[4]; bf16x8 v; } r;
  r.u[0] = x0; r.u[1] = x1; r.u[2] = y0; r.u[3] = y1;
  return r.v;
}

__device__ __forceinline__ bf16x8 pack8(f32x4 p0, f32x4 p1) {
  bf16x8 o;
  o[0] = (short)f2bf(p0[0]); o[1] = (short)f2bf(p0[1]);
  o[2] = (short)f2bf(p0[2]); o[3] = (short)f2bf(p0[3]);
  o[4] = (short)f2bf(p1[0]); o[5] = (short)f2bf(p1[1]);
  o[6] = (short)f2bf(p1[2]); o[7] = (short)f2bf(p1[3]);
  return o;
}
// Fast frag-convert via v_cvt_pk_bf16_f32 (RNE)
__device__ __forceinline__ bf16x8 pack8q(f32x4 lo, f32x4 hi) {
  union { unsigned u[4]; bf16x8 v; } r;
  r.u[0] = cvtpk(lo[0], lo[1]); r.u[1] = cvtpk(lo[2], lo[3]);
  r.u[2] = cvtpk(hi[0], hi[1]); r.u[3] = cvtpk(hi[2], hi[3]);
  return r.v;
}

// ---------------------------------------------------------------- cvt f32->bf16
__global__ __launch_bounds__(256) void cvt_kernel(const float* __restrict__ src,
                                                  unsigned short* __restrict__ dst,
                                                  int n8) {
  int i = blockIdx.x * blockDim.x + threadIdx.x;
  if (i >= n8) return;
  const f32x4* s = (const f32x4*)src;
  f32x4 x = s[2 * i], y = s[2 * i + 1];
  ((bf16x8*)dst)[i] = pack8(x, y);
}

// ---------------------------------------------------------------- add partials
// c21(bf16) = bf16( f32(p0) + f32(p1) )   (bf16 q-half partials)
__global__ __launch_bounds__(256) void addcvt_kernel(const unsigned short* __restrict__ p0,
                                                     const unsigned short* __restrict__ p1,
                                                     unsigned short* __restrict__ dst,
                                                     int n8) {
  int i = blockIdx.x * blockDim.x + threadIdx.x;
  if (i >= n8) return;
  bf16x8 a = ((const bf16x8*)p0)[i];
  bf16x8 b = ((const bf16x8*)p1)[i];
  bf16x8 o;
#pragma unroll
  for (int j = 0; j < 8; ++j)
    o[j] = (short)f2bf(bf2f((unsigned short)a[j]) + bf2f((unsigned short)b[j]));
  ((bf16x8*)dst)[i] = o;
}

// ---------------------------------------------------------------- staged GEMM
// A [rows,K] row-major (f32 if AF32, else bf16); W [1024,K] bf16 row-major.
// C = A @ W^T + bias. 128x128 tile, BK=32, reg-staged LDS, 2-phase with
// lgkmcnt-only barriers (R8-validated). AF32: cvt folded into LDS write.
// MODE 0: bf16 to [B,H,L,64]; MODE 2: f32 row-major [rows,1024]
template <int K, int MODE, bool AF32>
__device__ __forceinline__ void gemm_body(const void* __restrict__ Ap,
                                          const unsigned short* __restrict__ W,
                                          const float* __restrict__ bias,
                                          void* __restrict__ outp,
                                          int rowb, int colb) {
  __shared__ unsigned short As[128 * 40], Bs[128 * 40];
  const int tid = threadIdx.x, wave = tid >> 6, lane = tid & 63;
  const int lg = lane >> 4, lm = lane & 15;
  const int wrow = (wave >> 1) * 64, wcol = (wave & 1) * 64;
  const int sr = tid >> 1, sh = (tid & 1) * 16;
  const unsigned short* Arow = AF32 ? nullptr
      : (const unsigned short*)Ap + (size_t)(rowb + sr) * K + sh;
  const float* ArowF = AF32 ? (const float*)Ap + (size_t)(rowb + sr) * K + sh
                            : nullptr;
  const unsigned short* Wrow = W + (size_t)(colb + sr) * K + sh;

  f32x4 acc[4][4];
#pragma unroll
  for (int i = 0; i < 4; ++i)
#pragma unroll
    for (int j = 0; j < 4; ++j) acc[i][j] = (f32x4){0.f, 0.f, 0.f, 0.f};

  f32x4 fa0, fa1, fa2, fa3;
  bf16x8 a0, a1, b0, b1;
  if (AF32) {
    fa0 = *(const f32x4*)(ArowF);     fa1 = *(const f32x4*)(ArowF + 4);
    fa2 = *(const f32x4*)(ArowF + 8); fa3 = *(const f32x4*)(ArowF + 12);
  } else {
    a0 = *(const bf16x8*)(Arow);
    a1 = *(const bf16x8*)(Arow + 8);
  }
  b0 = *(const bf16x8*)(Wrow);
  b1 = *(const bf16x8*)(Wrow + 8);

  for (int kk = 0; kk < K; kk += 32) {
    lds_barrier();   // previous iteration's LDS frag reads complete
    if (AF32) {
      *(bf16x8*)&As[sr * 40 + sh]     = pack8q(fa0, fa1);
      *(bf16x8*)&As[sr * 40 + sh + 8] = pack8q(fa2, fa3);
    } else {
      *(bf16x8*)&As[sr * 40 + sh] = a0;
      *(bf16x8*)&As[sr * 40 + sh + 8] = a1;
    }
    *(bf16x8*)&Bs[sr * 40 + sh] = b0;
    *(bf16x8*)&Bs[sr * 40 + sh + 8] = b1;
    const int kn = (kk + 32 < K) ? kk + 32 : 0;   // clamped harmless reload
    if (AF32) {
      fa0 = *(const f32x4*)(ArowF + kn);     fa1 = *(const f32x4*)(ArowF + kn + 4);
      fa2 = *(const f32x4*)(ArowF + kn + 8); fa3 = *(const f32x4*)(ArowF + kn + 12);
    } else {
      a0 = *(const bf16x8*)(Arow + kn);
      a1 = *(const bf16x8*)(Arow + kn + 8);
    }
    b0 = *(const bf16x8*)(Wrow + kn);
    b1 = *(const bf16x8*)(Wrow + kn + 8);
    lds_barrier();   // staged writes visible
    bf16x8 af[4], wf[4];
#pragma unroll
    for (int i = 0; i < 4; ++i) af[i] = *(const bf16x8*)&As[(wrow + i * 16 + lm) * 40 + lg * 8];
#pragma unroll
    for (int j = 0; j < 4; ++j) wf[j] = *(const bf16x8*)&Bs[(wcol + j * 16 + lm) * 40 + lg * 8];
#pragma unroll
    for (int i = 0; i < 4; ++i)
#pragma unroll
      for (int j = 0; j < 4; ++j) acc[i][j] = mfma16(af[i], wf[j], acc[i][j]);
  }

#pragma unroll
  for (int j = 0; j < 4; ++j) {
    int col = colb + wcol + j * 16 + lm;
    float bs = bias[col];
#pragma unroll
    for (int i = 0; i < 4; ++i) {
#pragma unroll
      for (int r = 0; r < 4; ++r) {
        int row = rowb + wrow + i * 16 + lg * 4 + r;
        float v = acc[i][j][r] + bs;
        if (MODE == 0) {
          int l = row >> 3, bb = row & 7, h = col >> 6, d = col & 63;
          ((unsigned short*)outp)[(((size_t)(bb * HN + h)) * LQ + l) * DPH + d] = f2bf(v);
        } else {
          ((float*)outp)[(size_t)row * MN + col] = v;
        }
      }
    }
  }
}

// Paired projections (f32 A, cvt folded). sel in blockIdx.y-MSB so the K/V
// pair sharing an A-panel has the SAME blockIdx.x -> same XCD (R14).
template <int K>
__global__ __launch_bounds__(256) void gemm_pair_f32_kernel(
    const float* __restrict__ A,
    const unsigned short* __restrict__ W0, const unsigned short* __restrict__ W1,
    const float* __restrict__ b0, const float* __restrict__ b1,
    void* __restrict__ o0, void* __restrict__ o1) {
  const int sel = blockIdx.y >> 3;
  gemm_body<K, 0, true>(A, sel ? W1 : W0, sel ? b1 : b0, sel ? o1 : o0,
                        blockIdx.x * 128, (blockIdx.y & 7) * 128);
}

// Dual final projections in one dispatch: blockIdx.y>=8 -> second problem.
template <int K>
__global__ __launch_bounds__(256) void gemm_dual_kernel(
    const unsigned short* __restrict__ A0, const unsigned short* __restrict__ A1,
    const unsigned short* __restrict__ W0, const unsigned short* __restrict__ W1,
    const float* __restrict__ b0, const float* __restrict__ b1,
    void* __restrict__ o0, void* __restrict__ o1) {
  const int sel = blockIdx.y >> 3;
  gemm_body<K, 2, false>(sel ? A1 : A0, sel ? W1 : W0, sel ? b1 : b0,
                         sel ? o1 : o0, blockIdx.x * 128, (blockIdx.y & 7) * 128);
}

// ---------------------------------------------------------------- V transpose
// V [BH, L, 64] bf16 -> VT [BH, 64, L]; optional per-source-row scale (1/colsum)
__global__ __launch_bounds__(256) void transpose_kernel(const unsigned short* __restrict__ V,
                                                        unsigned short* __restrict__ VT,
                                                        const float* __restrict__ scale) {
  __shared__ unsigned short t[64][72];
  int bh = blockIdx.y, l0 = blockIdx.x * 64;
  int tid = threadIdx.x;
  int r = tid >> 2, c0 = (tid & 3) * 16;
  const unsigned short* src = V + ((size_t)bh * LQ + l0 + r) * DPH + c0;
  bf16x8 v0 = *(const bf16x8*)(src);
  bf16x8 v1 = *(const bf16x8*)(src + 8);
  if (scale) {
    float sc = scale[(size_t)bh * LQ + l0 + r];
#pragma unroll
    for (int j = 0; j < 8; ++j) {
      v0[j] = (short)f2bf(bf2f((unsigned short)v0[j]) * sc);
      v1[j] = (short)f2bf(bf2f((unsigned short)v1[j]) * sc);
    }
  }
  *(bf16x8*)&t[r][c0] = v0;
  *(bf16x8*)&t[r][c0 + 8] = v1;
  __syncthreads();
  int d = tid >> 2, lc = (tid & 3) * 16;
  bf16x8 o0, o1;
#pragma unroll
  for (int j = 0; j < 8; ++j) {
    o0[j] = (short)t[lc + j][d];
    o1[j] = (short)t[lc + 8 + j][d];
  }
  unsigned short* dst = VT + ((size_t)bh * DPH + d) * LQ + l0 + lc;
  *(bf16x8*)dst = o0;
  *(bf16x8*)(dst + 8) = o1;
}

// ---------------------------------------------------------------- col reduce
// inv_colsum[bh,k] = 1/sum_q exp(s[q,k]).  bh-major grid (R14, XCD-local).
__global__ __launch_bounds__(256) void col_reduce_kernel(const unsigned short* __restrict__ K1p,
                                                         const unsigned short* __restrict__ K2p,
                                                         float* __restrict__ inv_colsum) {
  int bh = blockIdx.x, kb = blockIdx.y * 128;
  int wave = threadIdx.x >> 6, lane = threadIdx.x & 63, l31 = lane & 31, sg = lane >> 5;
  int k0w = kb + wave * 32;
  const unsigned short* k1 = K1p + (size_t)bh * LQ * DPH;
  const unsigned short* k2 = K2p + (size_t)bh * LQ * DPH;
  bf16x8 bk[4];
#pragma unroll
  for (int i = 0; i < 4; ++i)
    bk[i] = *(const bf16x8*)(k1 + (size_t)(k0w + l31) * DPH + i * 16 + sg * 8);
  float tot = 0.f;
  for (int q0 = 0; q0 < LQ; q0 += 32) {
    bf16x8 aq[4];
#pragma unroll
    for (int i = 0; i < 4; ++i)
      aq[i] = *(const bf16x8*)(k2 + (size_t)(q0 + l31) * DPH + i * 16 + sg * 8);
    f32x16 cs = zero16();
#pragma unroll
    for (int i = 0; i < 4; ++i) cs = mfma32(aq[i], bk[i], cs);
#pragma unroll
    for (int r = 0; r < 16; ++r) tot += __expf(cs[r]);
  }
  tot += __shfl_xor(tot, 32);
  if (lane < 32) inv_colsum[(size_t)bh * LQ + k0w + lane] = 1.0f / tot;
}

// ---------------------------------------------------------------- ctx 1->2
// out[q][d] = sum_k exp(s[q,k]) * V1s[k][d]   (V1s pre-scaled by 1/colsum)
// bh-major grid (R14, XCD-local).
__global__ __launch_bounds__(256) void ctx12_kernel(const unsigned short* __restrict__ K1p,
                                                    const unsigned short* __restrict__ K2p,
                                                    const unsigned short* __restrict__ V1Ts,
                                                    unsigned short* __restrict__ c12) {
  int bh = blockIdx.x, b = bh >> 4, h = bh & 15;
  int wave = threadIdx.x >> 6, lane = threadIdx.x & 63, l31 = lane & 31, sg = lane >> 5;
  int q0 = blockIdx.y * 128 + wave * 32;
  const unsigned short* k1 = K1p + (size_t)bh * LQ * DPH;
  const unsigned short* k2 = K2p + (size_t)bh * LQ * DPH;
  const unsigned short* vt = V1Ts + (size_t)bh * DPH * LQ;

  bf16x8 bq[4];  // K2 rows q (B operand of score), hoisted
#pragma unroll
  for (int i = 0; i < 4; ++i)
    bq[i] = *(const bf16x8*)(k2 + (size_t)(q0 + l31) * DPH + i * 16 + sg * 8);

  f32x16 acc0 = zero16(), acc1 = zero16();
  for (int k0 = 0; k0 < LQ; k0 += 32) {
    bf16x8 ak[4];
#pragma unroll
    for (int i = 0; i < 4; ++i)
      ak[i] = *(const bf16x8*)(k1 + (size_t)(k0 + l31) * DPH + i * 16 + sg * 8);
    f32x16 cs = zero16();
#pragma unroll
    for (int i = 0; i < 4; ++i) cs = mfma32(ak[i], bq[i], cs);  // C[k][q]
    float p[16];
#pragma unroll
    for (int r = 0; r < 16; ++r) p[r] = __expf(cs[r]);
    bf16x8 pa0 = pfrag(p), pa1 = pfrag(p + 8);
    bf16x8 v00 = *(const bf16x8*)(vt + (size_t)l31 * LQ + k0 + sg * 8);
    bf16x8 v01 = *(const bf16x8*)(vt + (size_t)l31 * LQ + k0 + 16 + sg * 8);
    bf16x8 v10 = *(const bf16x8*)(vt + (size_t)(32 + l31) * LQ + k0 + sg * 8);
    bf16x8 v11 = *(const bf16x8*)(vt + (size_t)(32 + l31) * LQ + k0 + 16 + sg * 8);
    acc0 = mfma32(pa0, v00, acc0);
    acc0 = mfma32(pa1, v01, acc0);
    acc1 = mfma32(pa0, v10, acc1);
    acc1 = mfma32(pa1, v11, acc1);
  }
#pragma unroll
  for (int r = 0; r < 16; ++r) {
    int q = q0 + (r & 3) + 8 * (r >> 2) + 4 * sg;
    size_t base = ((size_t)q * BN + b) * MN + h * 64;
    c12[base + l31] = f2bf(acc0[r]);
    c12[base + 32 + l31] = f2bf(acc1[r]);
  }
}

// ---------------------------------------------------------------- ctx 2->1
// v10 = R15's VERIFIED body (pex kept in f32 regs across both barriers --
// NO cross-type strip re-read, the R16 NaN source) with NATURAL register
// allocation (R15 lesson: __launch_bounds__(1024,8) forced a 32-VGPR target
// -> 1.9GB scratch spill; v4's natural allocation measured exactly 64).
//   * bf16 strip (SPB=36): LDS 36.9KB + f32 tot 4.6KB = 41.5KB -> if VGPR
//     lands <=64, TWO 16-wave blocks co-reside per CU organically.
//   * q-split blockIdx.z in {0,1}: grid 512; bf16 partials merged by addcvt.
__global__ __launch_bounds__(1024) void ctx21_part_kernel(const unsigned short* __restrict__ K1p,
                                                          const unsigned short* __restrict__ K2p,
                                                          const unsigned short* __restrict__ V2T,
                                                          unsigned short* __restrict__ part) {
  constexpr int SPB = 36;               // bf16 per k-row (32 q + 4 pad; 72B rows)
  constexpr int WSB = 32 * SPB;         // bf16 per wave strip
  constexpr int SPT = 36;               // f32 per k-row of tot
  __shared__ unsigned short stripb[16 * WSB];  // 36864 B
  __shared__ float tot[32 * SPT];              // 4608 B  (total 41472 B)
  const int b = blockIdx.x, kb = blockIdx.y, qh = blockIdx.z;   // grid (8,32,2)
  const int tid = threadIdx.x, wave = tid >> 6, lane = tid & 63;
  const int l31 = lane & 31, sg = lane >> 5;
  const int h = wave, bh = b * HN + h;
  const int k0 = kb * 32;
  const unsigned short* k1 = K1p + (size_t)bh * LQ * DPH;
  const unsigned short* k2 = K2p + (size_t)bh * LQ * DPH;
  const unsigned short* vt = V2T + (size_t)bh * DPH * LQ;
  unsigned short* mystrip = &stripb[wave * WSB];

  const int tbeg = qh * 16, tend = tbeg + 16;   // q in [qh*512, qh*512+512)
  // stage-B map: 256 threads, each (k, q-quad): 16 bf16x4 reads
  const int bk_ = tid & 31, bq4 = (tid >> 5) * 4;

  bf16x8 bk[4];  // K1 rows k (score B operand), fixed for whole kernel
#pragma unroll
  for (int i = 0; i < 4; ++i)
    bk[i] = *(const bf16x8*)(k1 + (size_t)(k0 + l31) * DPH + i * 16 + sg * 8);

  // prologue: K2 fragments for first q-step of this half
  bf16x8 aq[4];
#pragma unroll
  for (int i = 0; i < 4; ++i)
    aq[i] = *(const bf16x8*)(k2 + (size_t)(tbeg * 32 + l31) * DPH + i * 16 + sg * 8);

  f32x16 acc0 = zero16(), acc1 = zero16();

  for (int t = tbeg; t < tend; ++t) {
    const int q0 = t * 32;
    // ---- stage A: scores (prefetched frags), exp -> pex (f32 regs), bf16
    //      strip write for the cross-head reduction
    f32x16 cs = zero16();
#pragma unroll
    for (int i = 0; i < 4; ++i) cs = mfma32(aq[i], bk[i], cs);  // C[row=q][col=k]
    const int qn = ((t + 1) & 31) * 32;   // harmless garbage prefetch on last
#pragma unroll
    for (int i = 0; i < 4; ++i)
      aq[i] = *(const bf16x8*)(k2 + (size_t)(qn + l31) * DPH + i * 16 + sg * 8);
    float pex[16];
#pragma unroll
    for (int r = 0; r < 16; ++r) pex[r] = __expf(cs[r]);
#pragma unroll
    for (int g = 0; g < 4; ++g) {         // q-group g covers q = g*8+4sg ..+3
      int qb = g * 8 + 4 * sg;
      *(unsigned*)&mystrip[l31 * SPB + qb]     = cvtpk(pex[4 * g],     pex[4 * g + 1]);
      *(unsigned*)&mystrip[l31 * SPB + qb + 2] = cvtpk(pex[4 * g + 2], pex[4 * g + 3]);
    }
    // V loads issued here; consumed after barrier B (vmcnt NOT drained at bar)
    bf16x8 v00 = *(const bf16x8*)(vt + (size_t)l31 * LQ + q0 + sg * 8);
    bf16x8 v01 = *(const bf16x8*)(vt + (size_t)l31 * LQ + q0 + 16 + sg * 8);
    bf16x8 v10 = *(const bf16x8*)(vt + (size_t)(32 + l31) * LQ + q0 + sg * 8);
    bf16x8 v11 = *(const bf16x8*)(vt + (size_t)(32 + l31) * LQ + q0 + 16 + sg * 8);
    lds_barrier();  // A: strips visible
    // ---- stage B: 256 threads, each sums one (k, q-quad) over 16 strips
    if (tid < 256) {
      int off = bk_ * SPB + bq4;
      f32x4 s = (f32x4){0.f, 0.f, 0.f, 0.f};
#pragma unroll
      for (int w = 0; w < 16; ++w) {
        bf16x4 v = *(const bf16x4*)&stripb[w * WSB + off];
        s[0] += bf2f((unsigned short)v[0]);
        s[1] += bf2f((unsigned short)v[1]);
        s[2] += bf2f((unsigned short)v[2]);
        s[3] += bf2f((unsigned short)v[3]);
      }
      f32x4 rc;
#pragma unroll
      for (int j = 0; j < 4; ++j) rc[j] = rcpf(s[j]);
      *(f32x4*)&tot[bk_ * SPT + bq4] = rc;
    }
    lds_barrier();  // B: tot visible
    // ---- stage C: tot reads, normalize with f32 pex, pfrag, PV MFMA
    float p8a[8], p8b[8];
#pragma unroll
    for (int g = 0; g < 4; ++g) {
      int qb = g * 8 + 4 * sg;
      f32x2 t0 = *(const f32x2*)&tot[l31 * SPT + qb];
      f32x2 t1 = *(const f32x2*)&tot[l31 * SPT + qb + 2];
      float* dstp = (g < 2) ? &p8a[(g & 1) * 4] : &p8b[(g & 1) * 4];
      dstp[0] = pex[4 * g]     * t0.x;
      dstp[1] = pex[4 * g + 1] * t0.y;
      dstp[2] = pex[4 * g + 2] * t1.x;
      dstp[3] = pex[4 * g + 3] * t1.y;
    }
    bf16x8 pa0 = pfrag(p8a), pa1 = pfrag(p8b);
    acc0 = mfma32(pa0, v00, acc0);
    acc0 = mfma32(pa1, v01, acc0);
    acc1 = mfma32(pa0, v10, acc1);
    acc1 = mfma32(pa1, v11, acc1);
  }
  // bf16 partial write for this q-half
  unsigned short* dst = part + (size_t)qh * (8192 * (size_t)MN);
#pragma unroll
  for (int r = 0; r < 16; ++r) {
    int k = k0 + (r & 3) + 8 * (r >> 2) + 4 * sg;
    size_t base = ((size_t)k * BN + b) * MN + h * 64;
    dst[base + l31] = f2bf(acc0[r]);
    dst[base + 32 + l31] = f2bf(acc1[r]);
  }
}

// ================================================================ host
extern "C" void kernel_launch(void* const* d_in, const int* in_sizes, int n_in,
                              void* d_out, int out_size, void* d_ws, size_t ws_size,
                              hipStream_t stream) {
  const float* ctx1 = (const float*)d_in[0];
  const float* ctx2 = (const float*)d_in[1];
  const float* Wk1 = (const float*)d_in[2];  const float* bk1 = (const float*)d_in[3];
  const float* Wv1 = (const float*)d_in[4];  const float* bv1 = (const float*)d_in[5];
  const float* Wk2 = (const float*)d_in[6];  const float* bk2 = (const float*)d_in[7];
  const float* Wv2 = (const float*)d_in[8];  const float* bv2 = (const float*)d_in[9];
  const float* Wf12 = (const float*)d_in[10]; const float* bf12 = (const float*)d_in[11];
  const float* Wf21 = (const float*)d_in[12]; const float* bf21 = (const float*)d_in[13];

  char* ws = (char*)d_ws;
  size_t off = 0;
  auto alloc = [&](size_t bytes) {
    void* p = ws + off;
    off += (bytes + 255) & ~(size_t)255;
    return p;
  };
  const size_t KV_BYTES = (size_t)BN * HN * LQ * DPH * 2;  // 16.78 MB

  unsigned short* wk1b = (unsigned short*)alloc((size_t)MN * D1N * 2);
  unsigned short* wv1b = (unsigned short*)alloc((size_t)MN * D1N * 2);
  unsigned short* wk2b = (unsigned short*)alloc((size_t)MN * D2N * 2);
  unsigned short* wv2b = (unsigned short*)alloc((size_t)MN * D2N * 2);
  unsigned short* wf12b = (unsigned short*)alloc((size_t)MN * MN * 2);
  unsigned short* wf21b = (unsigned short*)alloc((size_t)MN * MN * 2);
  unsigned short* K1buf = (unsigned short*)alloc(KV_BYTES);
  unsigned short* K2buf = (unsigned short*)alloc(KV_BYTES);
  unsigned short* V1T = (unsigned short*)alloc(KV_BYTES);   // scaled by 1/colsum
  unsigned short* V2T = (unsigned short*)alloc(KV_BYTES);
  float* invcs = (float*)alloc((size_t)BN * HN * LQ * 4);
  unsigned short* c12 = (unsigned short*)alloc(KV_BYTES);
  unsigned short* c21 = (unsigned short*)alloc(KV_BYTES);
  unsigned short* c21p = (unsigned short*)alloc((size_t)2 * 8192 * MN * 2);  // bf16 partials
  unsigned short* V1tmp = c12;  // alias: dead before c12 written
  unsigned short* V2tmp = c21;

  // ---- phase 1: weight f32 -> bf16 conversions (ctx cvt folded into GEMM)
  auto cvt = [&](const float* s, unsigned short* d, int n) {
    int n8 = n / 8;
    cvt_kernel<<<(n8 + 255) / 256, 256, 0, stream>>>(s, d, n8);
  };
  cvt(Wk1, wk1b, MN * D1N);
  cvt(Wv1, wv1b, MN * D1N);
  cvt(Wk2, wk2b, MN * D2N);
  cvt(Wv2, wv2b, MN * D2N);
  cvt(Wf12, wf12b, MN * MN);
  cvt(Wf21, wf21b, MN * MN);

  // ---- phase 2: projections, K/V paired per context (sel in y-MSB), f32 A
  gemm_pair_f32_kernel<D1N><<<dim3(64, 16), 256, 0, stream>>>(
      ctx1, wk1b, wv1b, bk1, bv1, K1buf, V1tmp);
  gemm_pair_f32_kernel<D2N><<<dim3(64, 16), 256, 0, stream>>>(
      ctx2, wk2b, wv2b, bk2, bv2, K2buf, V2tmp);

  // ---- phase 3: colsum reduction (bh-major grid), then V transposes
  col_reduce_kernel<<<dim3(BN * HN, LQ / 128), 256, 0, stream>>>(K1buf, K2buf, invcs);
  dim3 gt(LQ / 64, BN * HN);
  transpose_kernel<<<gt, 256, 0, stream>>>(V1tmp, V1T, invcs);
  transpose_kernel<<<gt, 256, 0, stream>>>(V2tmp, V2T, nullptr);

  // ---- phase 4: context passes (ctx21: q-split, natural-VGPR co-residency)
  ctx12_kernel<<<dim3(BN * HN, LQ / 128), 256, 0, stream>>>(K1buf, K2buf, V1T, c12);
  ctx21_part_kernel<<<dim3(BN, LQ / 32, 2), 1024, 0, stream>>>(K1buf, K2buf, V2T, c21p);
  addcvt_kernel<<<(8192 * MN / 8 + 255) / 256, 256, 0, stream>>>(
      c21p, c21p + (size_t)8192 * MN, c21, 8192 * MN / 8);

  // ---- phase 5: both final projections in ONE dispatch -> f32 d_out
  float* out0 = (float*)d_out;                 // [L1, B, M] (context_2_to_1)
  float* out1 = out0 + (size_t)LQ * BN * MN;   // [L2, B, M] (context_1_to_2)
  gemm_dual_kernel<MN><<<dim3(64, 16), 256, 0, stream>>>(
      c21, c12, wf21b, wf12b, bf21, bf12, out0, out1);
}

// Round 18
// 466.951 us; speedup vs baseline: 1.8838x; 1.0829x over previous
//
#include <hip/hip_runtime.h>
#include <hip/hip_bf16.h>

// Problem constants
constexpr int LQ  = 1024;  // L1 == L2 == 1024
constexpr int BN  = 8;
constexpr int D1N = 512;
constexpr int D2N = 1024;
constexpr int HN  = 16;
constexpr int MN  = 1024;
constexpr int DPH = 64;

typedef __attribute__((ext_vector_type(8)))  short bf16x8;   // 8 bf16 in 4 VGPRs
typedef __attribute__((ext_vector_type(2)))  float f32x2;
typedef __attribute__((ext_vector_type(4)))  float f32x4;
typedef __attribute__((ext_vector_type(16))) float f32x16;

__device__ __forceinline__ unsigned short f2bf(float f) {
  unsigned u = __float_as_uint(f);
  u += 0x7FFFu + ((u >> 16) & 1u);   // RNE
  return (unsigned short)(u >> 16);
}
__device__ __forceinline__ float bf2f(unsigned short u) {
  return __uint_as_float(((unsigned)u) << 16);
}
__device__ __forceinline__ float rcpf(float x) {
  float r;
  asm("v_rcp_f32 %0, %1" : "=v"(r) : "v"(x));
  return r;
}

__device__ __forceinline__ f32x4 mfma16(bf16x8 a, bf16x8 b, f32x4 c) {
  return __builtin_amdgcn_mfma_f32_16x16x32_bf16(a, b, c, 0, 0, 0);
}
__device__ __forceinline__ f32x16 mfma32(bf16x8 a, bf16x8 b, f32x16 c) {
  return __builtin_amdgcn_mfma_f32_32x32x16_bf16(a, b, c, 0, 0, 0);
}
__device__ __forceinline__ f32x16 zero16() {
  f32x16 z;
#pragma unroll
  for (int i = 0; i < 16; ++i) z[i] = 0.f;
  return z;
}

__device__ __forceinline__ unsigned cvtpk(float lo, float hi) {
  unsigned r;
  asm("v_cvt_pk_bf16_f32 %0, %1, %2" : "=v"(r) : "v"(lo), "v"(hi));
  return r;
}

// LDS-visibility barrier WITHOUT the vmcnt(0) drain __syncthreads() emits.
// (Correctness-proven R7-R17.)
__device__ __forceinline__ void lds_barrier() {
  asm volatile("s_waitcnt lgkmcnt(0)" ::: "memory");
  __builtin_amdgcn_s_barrier();
}

// Build PV A-fragment from 8 P values (C-layout row=(reg&3)+8*(reg>>2)+4*(lane>>5)).
__device__ __forceinline__ bf16x8 pfrag(const float* p) {
  unsigned x0 = cvtpk(p[0], p[1]), y0 = cvtpk(p[4], p[5]);
  unsigned x1 = cvtpk(p[2], p[3]), y1 = cvtpk(p[6], p[7]);
  asm volatile("v_permlane32_swap_b32 %0, %1" : "+v"(x0), "+v"(y0));
  asm volatile("v_permlane32_swap_b32 %0, %1" : "+v"(x1), "+v"(y1));
  union { unsigned u[4]; bf16x8 v; } r;
  r.u[0] = x0; r.u[1] = x1; r.u[2] = y0; r.u[3] = y1;
  return r.v;
}

__device__ __forceinline__ bf16x8 pack8(f32x4 p0, f32x4 p1) {
  bf16x8 o;
  o[0] = (short)f2bf(p0[0]); o[1] = (short)f2bf(p0[1]);
  o[2] = (short)f2bf(p0[2]); o[3] = (short)f2bf(p0[3]);
  o[4] = (short)f2bf(p1[0]); o[5] = (short)f2bf(p1[1]);
  o[6] = (short)f2bf(p1[2]); o[7] = (short)f2bf(p1[3]);
  return o;
}
// Fast frag-convert via v_cvt_pk_bf16_f32 (RNE)
__device__ __forceinline__ bf16x8 pack8q(f32x4 lo, f32x4 hi) {
  union { unsigned u[4]; bf16x8 v; } r;
  r.u[0] = cvtpk(lo[0], lo[1]); r.u[1] = cvtpk(lo[2], lo[3]);
  r.u[2] = cvtpk(hi[0], hi[1]); r.u[3] = cvtpk(hi[2], hi[3]);
  return r.v;
}

// ---------------------------------------------------------------- merged cvt
// All six weight f32->bf16 conversions in ONE dispatch (R18: saves ~5 launch
// overheads; the conversions are tiny and launch-latency dominated).
struct CvtArgs {
  const float* src[6];
  unsigned short* dst[6];
  int cum[7];   // cumulative x8-element counts
};
__global__ __launch_bounds__(256) void cvt6_kernel(CvtArgs a) {
  int i = blockIdx.x * blockDim.x + threadIdx.x;
  if (i >= a.cum[6]) return;
  int s = 0;
#pragma unroll
  for (int j = 1; j < 6; ++j) s += (i >= a.cum[j]) ? 1 : 0;
  int off = i - a.cum[s];
  const f32x4* sp = (const f32x4*)a.src[s];
  f32x4 x = sp[2 * off], y = sp[2 * off + 1];
  ((bf16x8*)a.dst[s])[off] = pack8(x, y);
}

// ---------------------------------------------------------------- staged GEMM
// A [rows,K] row-major (f32 if AF32, else bf16); W [1024,K] bf16 row-major.
// C = A @ W^T + bias. 128x128 tile, BK=32, reg-staged LDS, 2-phase with
// lgkmcnt-only barriers (R8-validated). AF32: cvt folded into LDS write.
// MODE 0: bf16 to [B,H,L,64]; MODE 2: f32 row-major [rows,1024]
template <int K, int MODE, bool AF32>
__device__ __forceinline__ void gemm_body(const void* __restrict__ Ap,
                                          const unsigned short* __restrict__ W,
                                          const float* __restrict__ bias,
                                          void* __restrict__ outp,
                                          int rowb, int colb) {
  __shared__ unsigned short As[128 * 40], Bs[128 * 40];
  const int tid = threadIdx.x, wave = tid >> 6, lane = tid & 63;
  const int lg = lane >> 4, lm = lane & 15;
  const int wrow = (wave >> 1) * 64, wcol = (wave & 1) * 64;
  const int sr = tid >> 1, sh = (tid & 1) * 16;
  const unsigned short* Arow = AF32 ? nullptr
      : (const unsigned short*)Ap + (size_t)(rowb + sr) * K + sh;
  const float* ArowF = AF32 ? (const float*)Ap + (size_t)(rowb + sr) * K + sh
                            : nullptr;
  const unsigned short* Wrow = W + (size_t)(colb + sr) * K + sh;

  f32x4 acc[4][4];
#pragma unroll
  for (int i = 0; i < 4; ++i)
#pragma unroll
    for (int j = 0; j < 4; ++j) acc[i][j] = (f32x4){0.f, 0.f, 0.f, 0.f};

  f32x4 fa0, fa1, fa2, fa3;
  bf16x8 a0, a1, b0, b1;
  if (AF32) {
    fa0 = *(const f32x4*)(ArowF);     fa1 = *(const f32x4*)(ArowF + 4);
    fa2 = *(const f32x4*)(ArowF + 8); fa3 = *(const f32x4*)(ArowF + 12);
  } else {
    a0 = *(const bf16x8*)(Arow);
    a1 = *(const bf16x8*)(Arow + 8);
  }
  b0 = *(const bf16x8*)(Wrow);
  b1 = *(const bf16x8*)(Wrow + 8);

  for (int kk = 0; kk < K; kk += 32) {
    lds_barrier();   // previous iteration's LDS frag reads complete
    if (AF32) {
      *(bf16x8*)&As[sr * 40 + sh]     = pack8q(fa0, fa1);
      *(bf16x8*)&As[sr * 40 + sh + 8] = pack8q(fa2, fa3);
    } else {
      *(bf16x8*)&As[sr * 40 + sh] = a0;
      *(bf16x8*)&As[sr * 40 + sh + 8] = a1;
    }
    *(bf16x8*)&Bs[sr * 40 + sh] = b0;
    *(bf16x8*)&Bs[sr * 40 + sh + 8] = b1;
    const int kn = (kk + 32 < K) ? kk + 32 : 0;   // clamped harmless reload
    if (AF32) {
      fa0 = *(const f32x4*)(ArowF + kn);     fa1 = *(const f32x4*)(ArowF + kn + 4);
      fa2 = *(const f32x4*)(ArowF + kn + 8); fa3 = *(const f32x4*)(ArowF + kn + 12);
    } else {
      a0 = *(const bf16x8*)(Arow + kn);
      a1 = *(const bf16x8*)(Arow + kn + 8);
    }
    b0 = *(const bf16x8*)(Wrow + kn);
    b1 = *(const bf16x8*)(Wrow + kn + 8);
    lds_barrier();   // staged writes visible
    bf16x8 af[4], wf[4];
#pragma unroll
    for (int i = 0; i < 4; ++i) af[i] = *(const bf16x8*)&As[(wrow + i * 16 + lm) * 40 + lg * 8];
#pragma unroll
    for (int j = 0; j < 4; ++j) wf[j] = *(const bf16x8*)&Bs[(wcol + j * 16 + lm) * 40 + lg * 8];
#pragma unroll
    for (int i = 0; i < 4; ++i)
#pragma unroll
      for (int j = 0; j < 4; ++j) acc[i][j] = mfma16(af[i], wf[j], acc[i][j]);
  }

#pragma unroll
  for (int j = 0; j < 4; ++j) {
    int col = colb + wcol + j * 16 + lm;
    float bs = bias[col];
#pragma unroll
    for (int i = 0; i < 4; ++i) {
#pragma unroll
      for (int r = 0; r < 4; ++r) {
        int row = rowb + wrow + i * 16 + lg * 4 + r;
        float v = acc[i][j][r] + bs;
        if (MODE == 0) {
          int l = row >> 3, bb = row & 7, h = col >> 6, d = col & 63;
          ((unsigned short*)outp)[(((size_t)(bb * HN + h)) * LQ + l) * DPH + d] = f2bf(v);
        } else {
          ((float*)outp)[(size_t)row * MN + col] = v;
        }
      }
    }
  }
}

// Paired projections (f32 A, cvt folded). sel in blockIdx.y-MSB so the K/V
// pair sharing an A-panel has the SAME blockIdx.x -> same XCD (R14).
template <int K>
__global__ __launch_bounds__(256) void gemm_pair_f32_kernel(
    const float* __restrict__ A,
    const unsigned short* __restrict__ W0, const unsigned short* __restrict__ W1,
    const float* __restrict__ b0, const float* __restrict__ b1,
    void* __restrict__ o0, void* __restrict__ o1) {
  const int sel = blockIdx.y >> 3;
  gemm_body<K, 0, true>(A, sel ? W1 : W0, sel ? b1 : b0, sel ? o1 : o0,
                        blockIdx.x * 128, (blockIdx.y & 7) * 128);
}

// Dual final projections in one dispatch: blockIdx.y>=8 -> second problem.
template <int K>
__global__ __launch_bounds__(256) void gemm_dual_kernel(
    const unsigned short* __restrict__ A0, const unsigned short* __restrict__ A1,
    const unsigned short* __restrict__ W0, const unsigned short* __restrict__ W1,
    const float* __restrict__ b0, const float* __restrict__ b1,
    void* __restrict__ o0, void* __restrict__ o1) {
  const int sel = blockIdx.y >> 3;
  gemm_body<K, 2, false>(sel ? A1 : A0, sel ? W1 : W0, sel ? b1 : b0,
                         sel ? o1 : o0, blockIdx.x * 128, (blockIdx.y & 7) * 128);
}

// ---------------------------------------------------------------- V transpose
// BOTH V transposes in one dispatch (grid.z: 0 = V1 scaled, 1 = V2 plain).
__global__ __launch_bounds__(256) void transpose2_kernel(
    const unsigned short* __restrict__ V1, unsigned short* __restrict__ VT1,
    const float* __restrict__ scale1,
    const unsigned short* __restrict__ V2, unsigned short* __restrict__ VT2) {
  __shared__ unsigned short t[64][72];
  const int which = blockIdx.z;
  const unsigned short* V = which ? V2 : V1;
  unsigned short* VT = which ? VT2 : VT1;
  const float* scale = which ? nullptr : scale1;
  int bh = blockIdx.y, l0 = blockIdx.x * 64;
  int tid = threadIdx.x;
  int r = tid >> 2, c0 = (tid & 3) * 16;
  const unsigned short* src = V + ((size_t)bh * LQ + l0 + r) * DPH + c0;
  bf16x8 v0 = *(const bf16x8*)(src);
  bf16x8 v1 = *(const bf16x8*)(src + 8);
  if (scale) {
    float sc = scale[(size_t)bh * LQ + l0 + r];
#pragma unroll
    for (int j = 0; j < 8; ++j) {
      v0[j] = (short)f2bf(bf2f((unsigned short)v0[j]) * sc);
      v1[j] = (short)f2bf(bf2f((unsigned short)v1[j]) * sc);
    }
  }
  *(bf16x8*)&t[r][c0] = v0;
  *(bf16x8*)&t[r][c0 + 8] = v1;
  __syncthreads();
  int d = tid >> 2, lc = (tid & 3) * 16;
  bf16x8 o0, o1;
#pragma unroll
  for (int j = 0; j < 8; ++j) {
    o0[j] = (short)t[lc + j][d];
    o1[j] = (short)t[lc + 8 + j][d];
  }
  unsigned short* dst = VT + ((size_t)bh * DPH + d) * LQ + l0 + lc;
  *(bf16x8*)dst = o0;
  *(bf16x8*)(dst + 8) = o1;
}

// ---------------------------------------------------------------- col reduce
// inv_colsum[bh,k] = 1/sum_q exp(s[q,k]).  bh-major grid (R14, XCD-local).
// R18: register prefetch of next q-tile K2 frags (barrier-free loop; loads
// in flight under the MFMA+exp of the current tile).
__global__ __launch_bounds__(256) void col_reduce_kernel(const unsigned short* __restrict__ K1p,
                                                         const unsigned short* __restrict__ K2p,
                                                         float* __restrict__ inv_colsum) {
  int bh = blockIdx.x, kb = blockIdx.y * 128;
  int wave = threadIdx.x >> 6, lane = threadIdx.x & 63, l31 = lane & 31, sg = lane >> 5;
  int k0w = kb + wave * 32;
  const unsigned short* k1 = K1p + (size_t)bh * LQ * DPH;
  const unsigned short* k2 = K2p + (size_t)bh * LQ * DPH;
  bf16x8 bk[4];
#pragma unroll
  for (int i = 0; i < 4; ++i)
    bk[i] = *(const bf16x8*)(k1 + (size_t)(k0w + l31) * DPH + i * 16 + sg * 8);
  bf16x8 aq[4];
#pragma unroll
  for (int i = 0; i < 4; ++i)
    aq[i] = *(const bf16x8*)(k2 + (size_t)(l31) * DPH + i * 16 + sg * 8);
  float tot = 0.f;
  for (int q0 = 0; q0 < LQ; q0 += 32) {
    const int qn = (q0 + 32) & (LQ - 1);   // harmless wrap reload on last
    bf16x8 aqn[4];
#pragma unroll
    for (int i = 0; i < 4; ++i)
      aqn[i] = *(const bf16x8*)(k2 + (size_t)(qn + l31) * DPH + i * 16 + sg * 8);
    f32x16 cs = zero16();
#pragma unroll
    for (int i = 0; i < 4; ++i) cs = mfma32(aq[i], bk[i], cs);
#pragma unroll
    for (int r = 0; r < 16; ++r) tot += __expf(cs[r]);
#pragma unroll
    for (int i = 0; i < 4; ++i) aq[i] = aqn[i];
  }
  tot += __shfl_xor(tot, 32);
  if (lane < 32) inv_colsum[(size_t)bh * LQ + k0w + lane] = 1.0f / tot;
}

// ---------------------------------------------------------------- ctx 1->2
// out[q][d] = sum_k exp(s[q,k]) * V1s[k][d]   (V1s pre-scaled by 1/colsum)
// bh-major grid (R14, XCD-local). R18: register prefetch of next k-tile K1
// frags (barrier-free loop -> loads overlap score-MFMA + exp + PV).
__global__ __launch_bounds__(256) void ctx12_kernel(const unsigned short* __restrict__ K1p,
                                                    const unsigned short* __restrict__ K2p,
                                                    const unsigned short* __restrict__ V1Ts,
                                                    unsigned short* __restrict__ c12) {
  int bh = blockIdx.x, b = bh >> 4, h = bh & 15;
  int wave = threadIdx.x >> 6, lane = threadIdx.x & 63, l31 = lane & 31, sg = lane >> 5;
  int q0 = blockIdx.y * 128 + wave * 32;
  const unsigned short* k1 = K1p + (size_t)bh * LQ * DPH;
  const unsigned short* k2 = K2p + (size_t)bh * LQ * DPH;
  const unsigned short* vt = V1Ts + (size_t)bh * DPH * LQ;

  bf16x8 bq[4];  // K2 rows q (B operand of score), hoisted
#pragma unroll
  for (int i = 0; i < 4; ++i)
    bq[i] = *(const bf16x8*)(k2 + (size_t)(q0 + l31) * DPH + i * 16 + sg * 8);

  bf16x8 ak[4];
#pragma unroll
  for (int i = 0; i < 4; ++i)
    ak[i] = *(const bf16x8*)(k1 + (size_t)(l31) * DPH + i * 16 + sg * 8);

  f32x16 acc0 = zero16(), acc1 = zero16();
  for (int k0 = 0; k0 < LQ; k0 += 32) {
    const int kn = (k0 + 32) & (LQ - 1);   // harmless wrap reload on last
    bf16x8 akn[4];
#pragma unroll
    for (int i = 0; i < 4; ++i)
      akn[i] = *(const bf16x8*)(k1 + (size_t)(kn + l31) * DPH + i * 16 + sg * 8);
    f32x16 cs = zero16();
#pragma unroll
    for (int i = 0; i < 4; ++i) cs = mfma32(ak[i], bq[i], cs);  // C[k][q]
    float p[16];
#pragma unroll
    for (int r = 0; r < 16; ++r) p[r] = __expf(cs[r]);
    bf16x8 pa0 = pfrag(p), pa1 = pfrag(p + 8);
    bf16x8 v00 = *(const bf16x8*)(vt + (size_t)l31 * LQ + k0 + sg * 8);
    bf16x8 v01 = *(const bf16x8*)(vt + (size_t)l31 * LQ + k0 + 16 + sg * 8);
    bf16x8 v10 = *(const bf16x8*)(vt + (size_t)(32 + l31) * LQ + k0 + sg * 8);
    bf16x8 v11 = *(const bf16x8*)(vt + (size_t)(32 + l31) * LQ + k0 + 16 + sg * 8);
    acc0 = mfma32(pa0, v00, acc0);
    acc0 = mfma32(pa1, v01, acc0);
    acc1 = mfma32(pa0, v10, acc1);
    acc1 = mfma32(pa1, v11, acc1);
#pragma unroll
    for (int i = 0; i < 4; ++i) ak[i] = akn[i];
  }
#pragma unroll
  for (int r = 0; r < 16; ++r) {
    int q = q0 + (r & 3) + 8 * (r >> 2) + 4 * sg;
    size_t base = ((size_t)q * BN + b) * MN + h * 64;
    c12[base + l31] = f2bf(acc0[r]);
    c12[base + 32 + l31] = f2bf(acc1[r]);
  }
}

// ---------------------------------------------------------------- ctx 2->1 FUSED
// v4 (R8/R14, best measured 131us): raw lds_barrier (no vmcnt drain -> V
// loads span 2 barriers, K2 loads prefetched one step ahead). Verified.
// R17 lesson: co-residency of two 16-wave blocks requires VGPR<64 (HW wave
// budget halves AT 64), unreachable for this kernel -> keep 1 blk/CU form.
__global__ __launch_bounds__(1024) void ctx21_fused_kernel(const unsigned short* __restrict__ K1p,
                                                           const unsigned short* __restrict__ K2p,
                                                           const unsigned short* __restrict__ V2T,
                                                           unsigned short* __restrict__ c21) {
  constexpr int SP = 34;              // floats per k-row (pad)
  constexpr int WS = 32 * SP;         // 1088 floats per wave strip
  __shared__ float strip[16 * WS];    // 69632 B
  __shared__ float tot[WS];           // tot[k][q] = 1/sum_h
  const int b = blockIdx.x, kb = blockIdx.y;   // grid (8, 32)
  const int tid = threadIdx.x, wave = tid >> 6, lane = tid & 63;
  const int l31 = lane & 31, sg = lane >> 5;
  const int h = wave, bh = b * HN + h;
  const int k0 = kb * 32;
  const unsigned short* k1 = K1p + (size_t)bh * LQ * DPH;
  const unsigned short* k2 = K2p + (size_t)bh * LQ * DPH;
  const unsigned short* vt = V2T + (size_t)bh * DPH * LQ;
  float* mystrip = &strip[wave * WS];

  const int bk_ = tid & 31, bq2 = (tid >> 5) * 2;   // stage-B cell map

  bf16x8 bk[4];  // K1 rows k (score B operand), fixed for whole kernel
#pragma unroll
  for (int i = 0; i < 4; ++i)
    bk[i] = *(const bf16x8*)(k1 + (size_t)(k0 + l31) * DPH + i * 16 + sg * 8);

  // prologue: K2 fragments for q-step 0
  bf16x8 aq[4];
#pragma unroll
  for (int i = 0; i < 4; ++i)
    aq[i] = *(const bf16x8*)(k2 + (size_t)(l31) * DPH + i * 16 + sg * 8);

  f32x16 acc0 = zero16(), acc1 = zero16();

  for (int t = 0; t < LQ / 32; ++t) {
    const int q0 = t * 32;
    // ---- stage A: scores for THIS head (prefetched frags), exp, strip write
    f32x16 cs = zero16();
#pragma unroll
    for (int i = 0; i < 4; ++i) cs = mfma32(aq[i], bk[i], cs);  // C[row=q][col=k]
    // prefetch next step's K2 fragments (in flight across both barriers)
    const int qn = ((t + 1) & 31) * 32;
#pragma unroll
    for (int i = 0; i < 4; ++i)
      aq[i] = *(const bf16x8*)(k2 + (size_t)(qn + l31) * DPH + i * 16 + sg * 8);
    float pex[16];
#pragma unroll
    for (int r = 0; r < 16; ++r) pex[r] = __expf(cs[r]);
#pragma unroll
    for (int g = 0; g < 4; ++g) {           // q-group g covers q = g*8+4sg ..+3
      int qb = g * 8 + 4 * sg;
      *(f32x2*)&mystrip[l31 * SP + qb]     = (f32x2){pex[4 * g],     pex[4 * g + 1]};
      *(f32x2*)&mystrip[l31 * SP + qb + 2] = (f32x2){pex[4 * g + 2], pex[4 * g + 3]};
    }
    // V loads issued here; consumed after barrier B (vmcnt NOT drained at bar)
    bf16x8 v00 = *(const bf16x8*)(vt + (size_t)l31 * LQ + q0 + sg * 8);
    bf16x8 v01 = *(const bf16x8*)(vt + (size_t)l31 * LQ + q0 + 16 + sg * 8);
    bf16x8 v10 = *(const bf16x8*)(vt + (size_t)(32 + l31) * LQ + q0 + sg * 8);
    bf16x8 v11 = *(const bf16x8*)(vt + (size_t)(32 + l31) * LQ + q0 + 16 + sg * 8);
    lds_barrier();  // A: strips visible
    // ---- stage B: 512 threads sum one q-pair over 16 strips (b64 reads)
    if (tid < 512) {
      int off = bk_ * SP + bq2;
      f32x2 s = *(const f32x2*)&strip[off];
#pragma unroll
      for (int w = 1; w < 16; ++w) {
        f32x2 v = *(const f32x2*)&strip[w * WS + off];
        s.x += v.x; s.y += v.y;
      }
      f32x2 rc; rc.x = rcpf(s.x); rc.y = rcpf(s.y);
      *(f32x2*)&tot[off] = rc;
    }
    lds_barrier();  // B: tot visible
    // ---- stage C: b64 tot reads, normalize in-reg, pfrag, PV MFMA
    float p8a[8], p8b[8];
#pragma unroll
    for (int g = 0; g < 4; ++g) {
      int qb = g * 8 + 4 * sg;
      f32x2 t0 = *(const f32x2*)&tot[l31 * SP + qb];
      f32x2 t1 = *(const f32x2*)&tot[l31 * SP + qb + 2];
      float* dstp = (g < 2) ? &p8a[(g & 1) * 4] : &p8b[(g & 1) * 4];
      dstp[0] = pex[4 * g]     * t0.x;
      dstp[1] = pex[4 * g + 1] * t0.y;
      dstp[2] = pex[4 * g + 2] * t1.x;
      dstp[3] = pex[4 * g + 3] * t1.y;
    }
    bf16x8 pa0 = pfrag(p8a), pa1 = pfrag(p8b);
    acc0 = mfma32(pa0, v00, acc0);
    acc0 = mfma32(pa1, v01, acc0);
    acc1 = mfma32(pa0, v10, acc1);
    acc1 = mfma32(pa1, v11, acc1);
  }
#pragma unroll
  for (int r = 0; r < 16; ++r) {
    int k = k0 + (r & 3) + 8 * (r >> 2) + 4 * sg;
    size_t base = ((size_t)k * BN + b) * MN + h * 64;
    c21[base + l31] = f2bf(acc0[r]);
    c21[base + 32 + l31] = f2bf(acc1[r]);
  }
}

// ================================================================ host
extern "C" void kernel_launch(void* const* d_in, const int* in_sizes, int n_in,
                              void* d_out, int out_size, void* d_ws, size_t ws_size,
                              hipStream_t stream) {
  const float* ctx1 = (const float*)d_in[0];
  const float* ctx2 = (const float*)d_in[1];
  const float* Wk1 = (const float*)d_in[2];  const float* bk1 = (const float*)d_in[3];
  const float* Wv1 = (const float*)d_in[4];  const float* bv1 = (const float*)d_in[5];
  const float* Wk2 = (const float*)d_in[6];  const float* bk2 = (const float*)d_in[7];
  const float* Wv2 = (const float*)d_in[8];  const float* bv2 = (const float*)d_in[9];
  const float* Wf12 = (const float*)d_in[10]; const float* bf12 = (const float*)d_in[11];
  const float* Wf21 = (const float*)d_in[12]; const float* bf21 = (const float*)d_in[13];

  char* ws = (char*)d_ws;
  size_t off = 0;
  auto alloc = [&](size_t bytes) {
    void* p = ws + off;
    off += (bytes + 255) & ~(size_t)255;
    return p;
  };
  const size_t KV_BYTES = (size_t)BN * HN * LQ * DPH * 2;  // 16.78 MB

  unsigned short* wk1b = (unsigned short*)alloc((size_t)MN * D1N * 2);
  unsigned short* wv1b = (unsigned short*)alloc((size_t)MN * D1N * 2);
  unsigned short* wk2b = (unsigned short*)alloc((size_t)MN * D2N * 2);
  unsigned short* wv2b = (unsigned short*)alloc((size_t)MN * D2N * 2);
  unsigned short* wf12b = (unsigned short*)alloc((size_t)MN * MN * 2);
  unsigned short* wf21b = (unsigned short*)alloc((size_t)MN * MN * 2);
  unsigned short* K1buf = (unsigned short*)alloc(KV_BYTES);
  unsigned short* K2buf = (unsigned short*)alloc(KV_BYTES);
  unsigned short* V1T = (unsigned short*)alloc(KV_BYTES);   // scaled by 1/colsum
  unsigned short* V2T = (unsigned short*)alloc(KV_BYTES);
  float* invcs = (float*)alloc((size_t)BN * HN * LQ * 4);
  unsigned short* c12 = (unsigned short*)alloc(KV_BYTES);
  unsigned short* c21 = (unsigned short*)alloc(KV_BYTES);
  unsigned short* V1tmp = c12;  // alias: dead before c12 written
  unsigned short* V2tmp = c21;

  // ---- phase 1: ALL weight f32 -> bf16 conversions in one dispatch
  {
    CvtArgs a;
    a.src[0] = Wk1;  a.dst[0] = wk1b;
    a.src[1] = Wv1;  a.dst[1] = wv1b;
    a.src[2] = Wk2;  a.dst[2] = wk2b;
    a.src[3] = Wv2;  a.dst[3] = wv2b;
    a.src[4] = Wf12; a.dst[4] = wf12b;
    a.src[5] = Wf21; a.dst[5] = wf21b;
    const int n1 = MN * D1N / 8, n2 = MN * D2N / 8, n3 = MN * MN / 8;
    a.cum[0] = 0;
    a.cum[1] = n1;
    a.cum[2] = 2 * n1;
    a.cum[3] = 2 * n1 + n2;
    a.cum[4] = 2 * n1 + 2 * n2;
    a.cum[5] = 2 * n1 + 2 * n2 + n3;
    a.cum[6] = 2 * n1 + 2 * n2 + 2 * n3;
    cvt6_kernel<<<(a.cum[6] + 255) / 256, 256, 0, stream>>>(a);
  }

  // ---- phase 2: projections, K/V paired per context (sel in y-MSB), f32 A
  gemm_pair_f32_kernel<D1N><<<dim3(64, 16), 256, 0, stream>>>(
      ctx1, wk1b, wv1b, bk1, bv1, K1buf, V1tmp);
  gemm_pair_f32_kernel<D2N><<<dim3(64, 16), 256, 0, stream>>>(
      ctx2, wk2b, wv2b, bk2, bv2, K2buf, V2tmp);

  // ---- phase 3: colsum reduction (bh-major grid), then both V transposes
  col_reduce_kernel<<<dim3(BN * HN, LQ / 128), 256, 0, stream>>>(K1buf, K2buf, invcs);
  transpose2_kernel<<<dim3(LQ / 64, BN * HN, 2), 256, 0, stream>>>(
      V1tmp, V1T, invcs, V2tmp, V2T);

  // ---- phase 4: context passes (separate kernels; bh-major ctx12 grid)
  ctx12_kernel<<<dim3(BN * HN, LQ / 128), 256, 0, stream>>>(K1buf, K2buf, V1T, c12);
  ctx21_fused_kernel<<<dim3(BN, LQ / 32), 1024, 0, stream>>>(K1buf, K2buf, V2T, c21);

  // ---- phase 5: both final projections in ONE dispatch -> f32 d_out
  float* out0 = (float*)d_out;                 // [L1, B, M] (context_2_to_1)
  float* out1 = out0 + (size_t)LQ * BN * MN;   // [L2, B, M] (context_1_to_2)
  gemm_dual_kernel<MN><<<dim3(64, 16), 256, 0, stream>>>(
      c21, c12, wf21b, wf12b, bf21, bf12, out0, out1);
}